// Round 14
// baseline (1113.367 us; speedup 1.0000x reference)
//
#include <hip/hip_runtime.h>
#include <hip/hip_bf16.h>
#include <math.h>

typedef __attribute__((ext_vector_type(4))) float f32x4;
typedef __attribute__((ext_vector_type(8))) short bf16x8;

__device__ __forceinline__ unsigned short f2bf(float f) {
  unsigned int x = __builtin_bit_cast(unsigned int, f);
  x += 0x7fffu + ((x >> 16) & 1u);
  return (unsigned short)(x >> 16);
}
__device__ __forceinline__ float bf2f(unsigned short u) {
  unsigned int x = ((unsigned int)u) << 16;
  return __builtin_bit_cast(float, x);
}

__device__ __forceinline__ void gload_lds16(const void* g, void* l) {
  __builtin_amdgcn_global_load_lds(
      (const __attribute__((address_space(1))) unsigned int*)g,
      (__attribute__((address_space(3))) unsigned int*)l, 16, 0, 0);
}

// ---------------- fused f32 -> bf16 weight casts ----------------
__global__ void cvt_all(const float* __restrict__ s0, int n0, const float* __restrict__ s1, int n1,
                        const float* __restrict__ s2, int n2, const float* __restrict__ s3, int n3,
                        unsigned short* __restrict__ d) {
  int i = blockIdx.x * 256 + threadIdx.x;
  if (i >= n0 + n1 + n2 + n3) return;
  const float* s;
  int off;
  if (i < n0) { s = s0; off = 0; }
  else if (i < n0 + n1) { s = s1; off = n0; }
  else if (i < n0 + n1 + n2) { s = s2; off = n0 + n1; }
  else { s = s3; off = n0 + n1 + n2; }
  d[i] = f2bf(s[i - off]);
}

// ---------------- LayerNorm, f32 input (REMAP: window gather + xb emit) ----------------
template <int REMAP>
__global__ __launch_bounds__(256)
void ln_kernel(const float* __restrict__ x, const float* __restrict__ g,
               const float* __restrict__ b, unsigned short* __restrict__ dst_o,
               unsigned short* __restrict__ xb) {
  int r = blockIdx.x * 4 + (threadIdx.x >> 6);
  int lane = threadIdx.x & 63;
  size_t src;
  if (REMAP) {
    int w = r >> 6, t = r & 63;
    int bb = w >> 8, wi = (w >> 4) & 15, wj = w & 15;
    int i = t >> 3, j = t & 7;
    int p = (wi * 8 + i + 4) & 127, q = (wj * 8 + j + 4) & 127;
    src = ((size_t)bb * 16384 + p * 128 + q) * 384;
  } else {
    src = (size_t)r * 384;
  }
  float v[6];
  float s = 0.f, s2 = 0.f;
#pragma unroll
  for (int m = 0; m < 6; ++m) {
    v[m] = x[src + lane + 64 * m];
    s += v[m];
    s2 += v[m] * v[m];
  }
  if (REMAP) {
#pragma unroll
    for (int m = 0; m < 6; ++m) xb[src + lane + 64 * m] = f2bf(v[m]);
  }
#pragma unroll
  for (int o2 = 1; o2 < 64; o2 <<= 1) {
    s += __shfl_xor(s, o2);
    s2 += __shfl_xor(s2, o2);
  }
  float mu = s * (1.f / 384.f);
  float var = s2 * (1.f / 384.f) - mu * mu;
  float ri = rsqrtf(var + 1e-5f);
  size_t dst = (size_t)r * 384;
#pragma unroll
  for (int m = 0; m < 6; ++m) {
    int c = lane + 64 * m;
    dst_o[dst + c] = f2bf((v[m] - mu) * ri * g[c] + b[c]);
  }
}

// ---------------- LayerNorm, bf16 input ----------------
__global__ __launch_bounds__(256)
void ln_bf16(const unsigned short* __restrict__ x, const float* __restrict__ g,
             const float* __restrict__ b, unsigned short* __restrict__ dst_o) {
  int r = blockIdx.x * 4 + (threadIdx.x >> 6);
  int lane = threadIdx.x & 63;
  size_t src = (size_t)r * 384;
  float v[6];
  float s = 0.f, s2 = 0.f;
#pragma unroll
  for (int m = 0; m < 3; ++m) {
    unsigned int u = *(const unsigned int*)&x[src + lane * 2 + 128 * m];
    v[2 * m] = bf2f((unsigned short)(u & 0xffffu));
    v[2 * m + 1] = bf2f((unsigned short)(u >> 16));
    s += v[2 * m] + v[2 * m + 1];
    s2 += v[2 * m] * v[2 * m] + v[2 * m + 1] * v[2 * m + 1];
  }
#pragma unroll
  for (int o2 = 1; o2 < 64; o2 <<= 1) {
    s += __shfl_xor(s, o2);
    s2 += __shfl_xor(s2, o2);
  }
  float mu = s * (1.f / 384.f);
  float var = s2 * (1.f / 384.f) - mu * mu;
  float ri = rsqrtf(var + 1e-5f);
#pragma unroll
  for (int m = 0; m < 3; ++m) {
    int c = lane * 2 + 128 * m;
    unsigned int lo = f2bf((v[2 * m] - mu) * ri * g[c] + b[c]);
    unsigned int hi = f2bf((v[2 * m + 1] - mu) * ri * g[c + 1] + b[c + 1]);
    *(unsigned int*)&dst_o[src + c] = lo | (hi << 16);
  }
}

// ---------------- GEMM: C(M,N) = A(M,K) * B(N,K)^T ----------------
// R13 structure (passed, 1111us) with COMPILE-TIME K/NT: nk is constexpr and
// the tile loop fully unrolls, so every gload_lds source address and ds_read
// address folds to base-VGPR + immediate offset (k*64B <= 3008 < 4096 imm).
// R13 diagnosis: VALUBusy 50% ~= 2x MfmaUtil — per-tile runtime address
// arithmetic was the wall (fc1@12 tiles == fc2@48 tiles time => not latency).
// BM=256, BN=128, BK=32, 512 thr / 8 waves (4Mx2N, wave 64x64, acc[4][4]).
// LDS 2x24KB. Protocol per tile: { stage(t+1) first; ds_read; setprio MFMA;
// __syncthreads() } — compiler's vmcnt(0)+lgkmcnt(0) drain = safety net.
// Swizzle (64B rows): LDS[row][g] = G[row][g ^ ((row>>1)&3)], both sides.
// EPI 0: bf16(acc+bias) | 1: bf16(gelu) | 2: proj scatter+bf16resid->bf16 | 3: f32+resid
template <int EPI, int K, int NT>
__global__ __launch_bounds__(512, 4)
void gemmT(const unsigned short* __restrict__ A, const unsigned short* __restrict__ Bw,
           const float* __restrict__ bias, int M, int N,
           unsigned short* __restrict__ Obf, const unsigned short* __restrict__ resid,
           float* __restrict__ Of) {
  __shared__ unsigned short lds[2 * 12288];  // per buf: A 256x32 (8192) + B 128x32 (4096)
  const int tid = threadIdx.x;
  const int lane = tid & 63;
  const int wid = tid >> 6;               // 0..7
  const int wm = wid >> 1, wn = wid & 1;  // wave grid 4M x 2N, wave tile 64x64
  const int li = lane & 15, lg = lane >> 4;

  // bijective XCD swizzle (m204)
  const int nwg = gridDim.x;
  const int orig = blockIdx.x;
  const int q = nwg >> 3, r = nwg & 7;
  const int xcd = orig & 7, loc = orig >> 3;
  const int wg = (xcd < r ? xcd * (q + 1) : r * (q + 1) + (xcd - r) * q) + loc;
  const int m0 = (wg / NT) * 256;
  const int n0 = (wg % NT) * 128;

  // staging: row = tid>>2 (0..127/round), grain = tid&3 (16B each);
  // pre-swizzled source grain = grain ^ ((row>>1)&3). A: 2 rounds; B: 1.
  const int srow = tid >> 2;
  const int scol = ((tid & 3) ^ ((srow >> 1) & 3)) * 8;
  const unsigned short* gA0 = A + (size_t)(m0 + srow) * K + scol;
  const unsigned short* gA1 = A + (size_t)(m0 + 128 + srow) * K + scol;
  const unsigned short* gB0 = Bw + (size_t)(n0 + srow) * K + scol;

  constexpr int nk = K >> 5;                   // 12 or 48, compile-time
  const int gsw = (lg ^ ((li >> 1) & 3)) * 8;  // frag-read swizzled grain
  f32x4 acc[4][4] = {};

  unsigned short* const buf0 = lds;
  unsigned short* const buf1 = lds + 12288;

  // prologue: stage tile 0, full drain
  gload_lds16(gA0, buf0 + wid * 512);
  gload_lds16(gA1, buf0 + 4096 + wid * 512);
  gload_lds16(gB0, buf0 + 8192 + wid * 512);
  __syncthreads();

#pragma unroll
  for (int t = 0; t < nk; ++t) {  // FULL unroll: all offsets become immediates
    unsigned short* const cur = (t & 1) ? buf1 : buf0;
    unsigned short* const nxt = (t & 1) ? buf0 : buf1;
    if (t + 1 < nk) {  // compile-time; k-offset = (t+1)*64 bytes, imm-foldable
      gload_lds16(gA0 + (t + 1) * 32, nxt + wid * 512);
      gload_lds16(gA1 + (t + 1) * 32, nxt + 4096 + wid * 512);
      gload_lds16(gB0 + (t + 1) * 32, nxt + 8192 + wid * 512);
    }
    bf16x8 a[4], b[4];
#pragma unroll
    for (int f = 0; f < 4; ++f) {
      a[f] = *(const bf16x8*)&cur[(wm * 64 + f * 16 + li) * 32 + gsw];
      b[f] = *(const bf16x8*)&cur[8192 + (wn * 64 + f * 16 + li) * 32 + gsw];
    }
    __builtin_amdgcn_s_setprio(1);
#pragma unroll
    for (int mf = 0; mf < 4; ++mf)
#pragma unroll
      for (int nf = 0; nf < 4; ++nf)
        acc[mf][nf] = __builtin_amdgcn_mfma_f32_16x16x32_bf16(a[mf], b[nf], acc[mf][nf], 0, 0, 0);
    __builtin_amdgcn_s_setprio(0);
    __syncthreads();  // full drain: ds_reads done, all waves' stage landed
  }

  // epilogue: C/D layout col = lane&15, row = (lane>>4)*4 + reg
#pragma unroll
  for (int mf = 0; mf < 4; ++mf) {
#pragma unroll
    for (int r2 = 0; r2 < 4; ++r2) {
      int mrow = m0 + wm * 64 + mf * 16 + lg * 4 + r2;
      size_t orow = (size_t)mrow;
      if (EPI == 2) {
        int w = mrow >> 6, t = mrow & 63;
        int bb2 = w >> 8, wi = (w >> 4) & 15, wj = w & 15;
        int i = t >> 3, j = t & 7;
        int p = (wi * 8 + i + 4) & 127, qq = (wj * 8 + j + 4) & 127;
        orow = (size_t)bb2 * 16384 + p * 128 + qq;
      }
#pragma unroll
      for (int nf = 0; nf < 4; ++nf) {
        int col = n0 + wn * 64 + nf * 16 + li;
        float v = acc[mf][nf][r2] + bias[col];
        if (EPI == 0) {
          Obf[(size_t)mrow * N + col] = f2bf(v);
        } else if (EPI == 1) {
          float y = 1.5957691f * (v + 0.044715f * v * v * v);
          float gl = v * __builtin_amdgcn_rcpf(1.f + __expf(-y));
          Obf[(size_t)mrow * N + col] = f2bf(gl);
        } else if (EPI == 2) {
          Obf[orow * 384 + col] = f2bf(v + bf2f(resid[orow * 384 + col]));
        } else {
          Of[(size_t)mrow * N + col] = v + bf2f(resid[(size_t)mrow * N + col]);
        }
      }
    }
  }
}

// ---------------- windowed attention: block = (window, head-triple); 4 waves ----------------
__global__ __launch_bounds__(256, 2)
void attn_kernel(const unsigned short* __restrict__ qkv, const float* __restrict__ btab,
                 const float* __restrict__ mask, unsigned short* __restrict__ out) {
  __shared__ unsigned short v_lds[4][64 * 40];  // V tile, row stride 40
  __shared__ unsigned short p_lds[4][64 * 72];  // P tile, row stride 72
  const int w = blockIdx.x;
  const int hi = blockIdx.y;  // 0..2
  const int tid = threadIdx.x;
  const int wid = tid >> 6, lane = tid & 63;
  const int li = lane & 15, lg = lane >> 4;
  const float* mrow = mask + (size_t)(w & 255) * 4096;
  const size_t base = (size_t)w * 64;
  const float SC = 0.17677669529663688f;  // 32^-0.5

  int h = wid * 3 + hi;
  bf16x8 aq[4], bk[4];
#pragma unroll
  for (int f = 0; f < 4; ++f) {
    size_t off = (base + f * 16 + li) * 1152 + h * 32 + lg * 8;
    aq[f] = *(const bf16x8*)&qkv[off];
    bk[f] = *(const bf16x8*)&qkv[off + 384];
  }
  f32x4 s[4][4] = {};
#pragma unroll
  for (int mf = 0; mf < 4; ++mf)
#pragma unroll
    for (int nf = 0; nf < 4; ++nf)
      s[mf][nf] = __builtin_amdgcn_mfma_f32_16x16x32_bf16(aq[mf], bk[nf], s[mf][nf], 0, 0, 0);

  {
    const unsigned short* vp = &qkv[(base + lane) * 1152 + 768 + h * 32];
    unsigned short* dp = &v_lds[wid][lane * 40];
#pragma unroll
    for (int c = 0; c < 4; ++c) *(bf16x8*)&dp[c * 8] = *(const bf16x8*)&vp[c * 8];
  }

#pragma unroll
  for (int mf = 0; mf < 4; ++mf) {
#pragma unroll
    for (int r = 0; r < 4; ++r) {
      int m = mf * 16 + lg * 4 + r;
      float mx = -1e30f;
#pragma unroll
      for (int nf = 0; nf < 4; ++nf) {
        int n = nf * 16 + li;
        int ridx = ((m >> 3) - (n >> 3) + 7) * 15 + (m & 7) - (n & 7) + 7;
        float val = s[mf][nf][r] * SC + btab[ridx * 12 + h] + mrow[m * 64 + n];
        s[mf][nf][r] = val;
        mx = fmaxf(mx, val);
      }
#pragma unroll
      for (int o2 = 1; o2 < 16; o2 <<= 1) mx = fmaxf(mx, __shfl_xor(mx, o2));
      float sum = 0.f;
#pragma unroll
      for (int nf = 0; nf < 4; ++nf) {
        float e = __expf(s[mf][nf][r] - mx);
        s[mf][nf][r] = e;
        sum += e;
      }
#pragma unroll
      for (int o2 = 1; o2 < 16; o2 <<= 1) sum += __shfl_xor(sum, o2);
      float inv = __builtin_amdgcn_rcpf(sum);
#pragma unroll
      for (int nf = 0; nf < 4; ++nf) s[mf][nf][r] *= inv;
    }
  }

#pragma unroll
  for (int mf = 0; mf < 4; ++mf)
#pragma unroll
    for (int nf = 0; nf < 4; ++nf)
#pragma unroll
      for (int r = 0; r < 4; ++r) {
        int m = mf * 16 + lg * 4 + r, n = nf * 16 + li;
        p_lds[wid][m * 72 + n] = f2bf(s[mf][nf][r]);
      }

  f32x4 o[4][2] = {};
#pragma unroll
  for (int kf = 0; kf < 2; ++kf) {
    bf16x8 bv[2];
#pragma unroll
    for (int df = 0; df < 2; ++df) {
      bf16x8 t;
#pragma unroll
      for (int e = 0; e < 8; ++e)
        t[e] = (short)v_lds[wid][(kf * 32 + lg * 8 + e) * 40 + df * 16 + li];
      bv[df] = t;
    }
#pragma unroll
    for (int mf = 0; mf < 4; ++mf) {
      bf16x8 pa = *(const bf16x8*)&p_lds[wid][(mf * 16 + li) * 72 + kf * 32 + lg * 8];
#pragma unroll
      for (int df = 0; df < 2; ++df)
        o[mf][df] = __builtin_amdgcn_mfma_f32_16x16x32_bf16(pa, bv[df], o[mf][df], 0, 0, 0);
    }
  }

#pragma unroll
  for (int mf = 0; mf < 4; ++mf)
#pragma unroll
    for (int df = 0; df < 2; ++df)
#pragma unroll
      for (int r = 0; r < 4; ++r) {
        size_t row = base + mf * 16 + lg * 4 + r;
        out[row * 384 + h * 32 + df * 16 + li] = f2bf(o[mf][df][r]);
      }
}

extern "C" void kernel_launch(void* const* d_in, const int* in_sizes, int n_in,
                              void* d_out, int out_size, void* d_ws, size_t ws_size,
                              hipStream_t stream) {
  const float* x      = (const float*)d_in[0];
  const float* qkv_w  = (const float*)d_in[1];
  const float* qkv_b  = (const float*)d_in[2];
  const float* proj_w = (const float*)d_in[3];
  const float* proj_b = (const float*)d_in[4];
  const float* rel    = (const float*)d_in[5];
  const float* g1     = (const float*)d_in[6];
  const float* b1     = (const float*)d_in[7];
  const float* g2     = (const float*)d_in[8];
  const float* b2     = (const float*)d_in[9];
  const float* fc1_w  = (const float*)d_in[10];
  const float* fc1_b  = (const float*)d_in[11];
  const float* fc2_w  = (const float*)d_in[12];
  const float* fc2_b  = (const float*)d_in[13];
  const float* mask   = (const float*)d_in[14];
  float* out = (float*)d_out;
  char* ws = (char*)d_ws;

  const int M = 131072;  // B * H * W tokens
  unsigned short* hw     = (unsigned short*)ws;
  unsigned short* qkv    = (unsigned short*)(ws + 100663296);
  unsigned short* hmid   = (unsigned short*)ws;
  unsigned short* attn_o = (unsigned short*)(ws + 402653184);
  unsigned short* ln2o   = attn_o;
  unsigned short* x1b    = (unsigned short*)(ws + 503316480);
  unsigned short* wq     = (unsigned short*)(ws + 603979776);
  unsigned short* wp     = wq + 442368;
  unsigned short* w1     = wp + 147456;
  unsigned short* w2     = w1 + 589824;
  unsigned short* xb     = (unsigned short*)(ws + 607518720);

  // fused weight casts (wq|wp|w1|w2 contiguous)
  cvt_all<<<(442368 + 147456 + 589824 + 589824 + 255) / 256, 256, 0, stream>>>(
      qkv_w, 442368, proj_w, 147456, fc1_w, 589824, fc2_w, 589824, wq);

  // LN1 + shift + window partition (also emits xb = bf16(x))
  ln_kernel<1><<<M / 4, 256, 0, stream>>>(x, g1, b1, hw, xb);

  // QKV projection: grid (M/256)*(1152/128) = 512*9
  gemmT<0, 384, 9><<<512 * 9, 512, 0, stream>>>(hw, wq, qkv_b, M, 1152, qkv, nullptr, nullptr);

  // windowed attention (one head-triple per block.y)
  attn_kernel<<<dim3(2048, 3), 256, 0, stream>>>(qkv, rel, mask, attn_o);

  // proj + window reverse + unshift + residual(xb bf16) -> x1 (bf16): 512*3
  gemmT<2, 384, 3><<<512 * 3, 512, 0, stream>>>(attn_o, wp, proj_b, M, 384, x1b, xb, nullptr);

  // LN2 (bf16 in)
  ln_bf16<<<M / 4, 256, 0, stream>>>(x1b, g2, b2, ln2o);

  // FC1 + GELU: 512*12
  gemmT<1, 384, 12><<<512 * 12, 512, 0, stream>>>(ln2o, w1, fc1_b, M, 1536, hmid, nullptr, nullptr);

  // FC2 + residual(x1 bf16) -> out (f32): 512*3
  gemmT<3, 1536, 3><<<512 * 3, 512, 0, stream>>>(hmid, w2, fc2_b, M, 384, nullptr, x1b, out);
}

// Round 15
// 1102.032 us; speedup vs baseline: 1.0103x; 1.0103x over previous
//
#include <hip/hip_runtime.h>
#include <hip/hip_bf16.h>
#include <math.h>

typedef __attribute__((ext_vector_type(4))) float f32x4;
typedef __attribute__((ext_vector_type(8))) short bf16x8;

__device__ __forceinline__ unsigned short f2bf(float f) {
  unsigned int x = __builtin_bit_cast(unsigned int, f);
  x += 0x7fffu + ((x >> 16) & 1u);
  return (unsigned short)(x >> 16);
}
__device__ __forceinline__ float bf2f(unsigned short u) {
  unsigned int x = ((unsigned int)u) << 16;
  return __builtin_bit_cast(float, x);
}

__device__ __forceinline__ void gload_lds16(const void* g, void* l) {
  __builtin_amdgcn_global_load_lds(
      (const __attribute__((address_space(1))) unsigned int*)g,
      (__attribute__((address_space(3))) unsigned int*)l, 16, 0, 0);
}

// ---------------- fused f32 -> bf16 weight casts ----------------
__global__ void cvt_all(const float* __restrict__ s0, int n0, const float* __restrict__ s1, int n1,
                        const float* __restrict__ s2, int n2, const float* __restrict__ s3, int n3,
                        unsigned short* __restrict__ d) {
  int i = blockIdx.x * 256 + threadIdx.x;
  if (i >= n0 + n1 + n2 + n3) return;
  const float* s;
  int off;
  if (i < n0) { s = s0; off = 0; }
  else if (i < n0 + n1) { s = s1; off = n0; }
  else if (i < n0 + n1 + n2) { s = s2; off = n0 + n1; }
  else { s = s3; off = n0 + n1 + n2; }
  d[i] = f2bf(s[i - off]);
}

// ---------------- LayerNorm, f32 input (REMAP: window gather + xb emit) ----------------
template <int REMAP>
__global__ __launch_bounds__(256)
void ln_kernel(const float* __restrict__ x, const float* __restrict__ g,
               const float* __restrict__ b, unsigned short* __restrict__ dst_o,
               unsigned short* __restrict__ xb) {
  int r = blockIdx.x * 4 + (threadIdx.x >> 6);
  int lane = threadIdx.x & 63;
  size_t src;
  if (REMAP) {
    int w = r >> 6, t = r & 63;
    int bb = w >> 8, wi = (w >> 4) & 15, wj = w & 15;
    int i = t >> 3, j = t & 7;
    int p = (wi * 8 + i + 4) & 127, q = (wj * 8 + j + 4) & 127;
    src = ((size_t)bb * 16384 + p * 128 + q) * 384;
  } else {
    src = (size_t)r * 384;
  }
  float v[6];
  float s = 0.f, s2 = 0.f;
#pragma unroll
  for (int m = 0; m < 6; ++m) {
    v[m] = x[src + lane + 64 * m];
    s += v[m];
    s2 += v[m] * v[m];
  }
  if (REMAP) {
#pragma unroll
    for (int m = 0; m < 6; ++m) xb[src + lane + 64 * m] = f2bf(v[m]);
  }
#pragma unroll
  for (int o2 = 1; o2 < 64; o2 <<= 1) {
    s += __shfl_xor(s, o2);
    s2 += __shfl_xor(s2, o2);
  }
  float mu = s * (1.f / 384.f);
  float var = s2 * (1.f / 384.f) - mu * mu;
  float ri = rsqrtf(var + 1e-5f);
  size_t dst = (size_t)r * 384;
#pragma unroll
  for (int m = 0; m < 6; ++m) {
    int c = lane + 64 * m;
    dst_o[dst + c] = f2bf((v[m] - mu) * ri * g[c] + b[c]);
  }
}

// ---------------- LayerNorm, bf16 input ----------------
__global__ __launch_bounds__(256)
void ln_bf16(const unsigned short* __restrict__ x, const float* __restrict__ g,
             const float* __restrict__ b, unsigned short* __restrict__ dst_o) {
  int r = blockIdx.x * 4 + (threadIdx.x >> 6);
  int lane = threadIdx.x & 63;
  size_t src = (size_t)r * 384;
  float v[6];
  float s = 0.f, s2 = 0.f;
#pragma unroll
  for (int m = 0; m < 3; ++m) {
    unsigned int u = *(const unsigned int*)&x[src + lane * 2 + 128 * m];
    v[2 * m] = bf2f((unsigned short)(u & 0xffffu));
    v[2 * m + 1] = bf2f((unsigned short)(u >> 16));
    s += v[2 * m] + v[2 * m + 1];
    s2 += v[2 * m] * v[2 * m] + v[2 * m + 1] * v[2 * m + 1];
  }
#pragma unroll
  for (int o2 = 1; o2 < 64; o2 <<= 1) {
    s += __shfl_xor(s, o2);
    s2 += __shfl_xor(s2, o2);
  }
  float mu = s * (1.f / 384.f);
  float var = s2 * (1.f / 384.f) - mu * mu;
  float ri = rsqrtf(var + 1e-5f);
#pragma unroll
  for (int m = 0; m < 3; ++m) {
    int c = lane * 2 + 128 * m;
    unsigned int lo = f2bf((v[2 * m] - mu) * ri * g[c] + b[c]);
    unsigned int hi = f2bf((v[2 * m + 1] - mu) * ri * g[c + 1] + b[c + 1]);
    *(unsigned int*)&dst_o[src + c] = lo | (hi << 16);
  }
}

// ---------------- GEMM: C(M,N) = A(M,K) * B(N,K)^T ----------------
// R14 + DEPTH-2 PIPELINE. Diagnosis (R13/R14): per-tile wall ~1930cy vs
// ~250cy compute — the __syncthreads vmcnt(0) drain serialized the full
// stage latency into every BK=32 tile. Fix: tri-buffer (3x24KB), counted
// vmcnt(3) per tile (stage(t) done, stage(t+1) IN FLIGHT — T4, never 0
// mid-loop), stage(t+2) issued post-barrier. Race-free fencing = R7's exact
// construction (passed + replayed): each wave waits ITS OWN vmcnt BEFORE
// s_barrier (so post-barrier all waves' stage(t) complete), and
// sched_barrier(0) after the barrier pins ds_reads below it (rule #18 —
// raw s_barrier is not a compiler fence; R12 omitted this and raced).
// Buffer indices/k-offsets compile-time (nk%3==0, full unroll).
// BM=256, BN=128, BK=32, 512 thr / 8 waves, wave 64x64, acc[4][4].
// Swizzle (64B rows): LDS[row][g] = G[row][g ^ ((row>>1)&3)], both sides.
// EPI 0: bf16(acc+bias) | 1: bf16(gelu) | 2: proj scatter+bf16resid->bf16 | 3: f32+resid
template <int EPI, int K, int NT>
__global__ __launch_bounds__(512, 4)
void gemmT(const unsigned short* __restrict__ A, const unsigned short* __restrict__ Bw,
           const float* __restrict__ bias, int M, int N,
           unsigned short* __restrict__ Obf, const unsigned short* __restrict__ resid,
           float* __restrict__ Of) {
  __shared__ unsigned short lds[3 * 12288];  // 3 bufs x (A 256x32 + B 128x32) = 72 KB
  const int tid = threadIdx.x;
  const int lane = tid & 63;
  const int wid = tid >> 6;               // 0..7
  const int wm = wid >> 1, wn = wid & 1;  // wave grid 4M x 2N, wave tile 64x64
  const int li = lane & 15, lg = lane >> 4;

  // bijective XCD swizzle (m204)
  const int nwg = gridDim.x;
  const int orig = blockIdx.x;
  const int q = nwg >> 3, r = nwg & 7;
  const int xcd = orig & 7, loc = orig >> 3;
  const int wg = (xcd < r ? xcd * (q + 1) : r * (q + 1) + (xcd - r) * q) + loc;
  const int m0 = (wg / NT) * 256;
  const int n0 = (wg % NT) * 128;

  // staging: row = tid>>2 (0..127/round), grain = tid&3 (16B each);
  // pre-swizzled source grain = grain ^ ((row>>1)&3). A: 2 rounds; B: 1.
  const int srow = tid >> 2;
  const int scol = ((tid & 3) ^ ((srow >> 1) & 3)) * 8;
  const unsigned short* gA0 = A + (size_t)(m0 + srow) * K + scol;
  const unsigned short* gA1 = A + (size_t)(m0 + 128 + srow) * K + scol;
  const unsigned short* gB0 = Bw + (size_t)(n0 + srow) * K + scol;

  constexpr int nk = K >> 5;                   // 12 or 48 (div by 3)
  const int gsw = (lg ^ ((li >> 1) & 3)) * 8;  // frag-read swizzled grain
  f32x4 acc[4][4] = {};

  // prologue: 2 stages in flight (tiles 0,1), no drain
  gload_lds16(gA0, lds + wid * 512);
  gload_lds16(gA1, lds + 4096 + wid * 512);
  gload_lds16(gB0, lds + 8192 + wid * 512);
  gload_lds16(gA0 + 32, lds + 12288 + wid * 512);
  gload_lds16(gA1 + 32, lds + 12288 + 4096 + wid * 512);
  gload_lds16(gB0 + 32, lds + 12288 + 8192 + wid * 512);

#pragma unroll
  for (int t = 0; t < nk; ++t) {  // full unroll: bufs & k-offsets constexpr
    // own stage(t) done; stage(t+1) stays in flight (counted, T4)
    if (t < nk - 1) {
      asm volatile("s_waitcnt vmcnt(3)" ::: "memory");
    } else {
      asm volatile("s_waitcnt vmcnt(0)" ::: "memory");
    }
    __builtin_amdgcn_s_barrier();        // all waves' stage(t) complete
    __builtin_amdgcn_sched_barrier(0);   // fence: nothing moves above (rule #18)
    unsigned short* const cur = lds + (t % 3) * 12288;
    if (t + 2 < nk) {  // stage 2 tiles ahead into buf (t+2)%3 (free: last read at t-1)
      unsigned short* const nxt = lds + ((t + 2) % 3) * 12288;
      gload_lds16(gA0 + (t + 2) * 32, nxt + wid * 512);
      gload_lds16(gA1 + (t + 2) * 32, nxt + 4096 + wid * 512);
      gload_lds16(gB0 + (t + 2) * 32, nxt + 8192 + wid * 512);
    }
    bf16x8 a[4], b[4];
#pragma unroll
    for (int f = 0; f < 4; ++f) {
      a[f] = *(const bf16x8*)&cur[(wm * 64 + f * 16 + li) * 32 + gsw];
      b[f] = *(const bf16x8*)&cur[8192 + (wn * 64 + f * 16 + li) * 32 + gsw];
    }
    __builtin_amdgcn_s_setprio(1);
#pragma unroll
    for (int mf = 0; mf < 4; ++mf)
#pragma unroll
      for (int nf = 0; nf < 4; ++nf)
        acc[mf][nf] = __builtin_amdgcn_mfma_f32_16x16x32_bf16(a[mf], b[nf], acc[mf][nf], 0, 0, 0);
    __builtin_amdgcn_s_setprio(0);
    // no trailing barrier: next tile's vmcnt+barrier is the sync point
  }

  // epilogue: C/D layout col = lane&15, row = (lane>>4)*4 + reg
#pragma unroll
  for (int mf = 0; mf < 4; ++mf) {
#pragma unroll
    for (int r2 = 0; r2 < 4; ++r2) {
      int mrow = m0 + wm * 64 + mf * 16 + lg * 4 + r2;
      size_t orow = (size_t)mrow;
      if (EPI == 2) {
        int w = mrow >> 6, t = mrow & 63;
        int bb2 = w >> 8, wi = (w >> 4) & 15, wj = w & 15;
        int i = t >> 3, j = t & 7;
        int p = (wi * 8 + i + 4) & 127, qq = (wj * 8 + j + 4) & 127;
        orow = (size_t)bb2 * 16384 + p * 128 + qq;
      }
#pragma unroll
      for (int nf = 0; nf < 4; ++nf) {
        int col = n0 + wn * 64 + nf * 16 + li;
        float v = acc[mf][nf][r2] + bias[col];
        if (EPI == 0) {
          Obf[(size_t)mrow * N + col] = f2bf(v);
        } else if (EPI == 1) {
          float y = 1.5957691f * (v + 0.044715f * v * v * v);
          float gl = v * __builtin_amdgcn_rcpf(1.f + __expf(-y));
          Obf[(size_t)mrow * N + col] = f2bf(gl);
        } else if (EPI == 2) {
          Obf[orow * 384 + col] = f2bf(v + bf2f(resid[orow * 384 + col]));
        } else {
          Of[(size_t)mrow * N + col] = v + bf2f(resid[(size_t)mrow * N + col]);
        }
      }
    }
  }
}

// ---------------- windowed attention: block = (window, head-triple); 4 waves ----------------
__global__ __launch_bounds__(256, 2)
void attn_kernel(const unsigned short* __restrict__ qkv, const float* __restrict__ btab,
                 const float* __restrict__ mask, unsigned short* __restrict__ out) {
  __shared__ unsigned short v_lds[4][64 * 40];  // V tile, row stride 40
  __shared__ unsigned short p_lds[4][64 * 72];  // P tile, row stride 72
  const int w = blockIdx.x;
  const int hi = blockIdx.y;  // 0..2
  const int tid = threadIdx.x;
  const int wid = tid >> 6, lane = tid & 63;
  const int li = lane & 15, lg = lane >> 4;
  const float* mrow = mask + (size_t)(w & 255) * 4096;
  const size_t base = (size_t)w * 64;
  const float SC = 0.17677669529663688f;  // 32^-0.5

  int h = wid * 3 + hi;
  bf16x8 aq[4], bk[4];
#pragma unroll
  for (int f = 0; f < 4; ++f) {
    size_t off = (base + f * 16 + li) * 1152 + h * 32 + lg * 8;
    aq[f] = *(const bf16x8*)&qkv[off];
    bk[f] = *(const bf16x8*)&qkv[off + 384];
  }
  f32x4 s[4][4] = {};
#pragma unroll
  for (int mf = 0; mf < 4; ++mf)
#pragma unroll
    for (int nf = 0; nf < 4; ++nf)
      s[mf][nf] = __builtin_amdgcn_mfma_f32_16x16x32_bf16(aq[mf], bk[nf], s[mf][nf], 0, 0, 0);

  {
    const unsigned short* vp = &qkv[(base + lane) * 1152 + 768 + h * 32];
    unsigned short* dp = &v_lds[wid][lane * 40];
#pragma unroll
    for (int c = 0; c < 4; ++c) *(bf16x8*)&dp[c * 8] = *(const bf16x8*)&vp[c * 8];
  }

#pragma unroll
  for (int mf = 0; mf < 4; ++mf) {
#pragma unroll
    for (int r = 0; r < 4; ++r) {
      int m = mf * 16 + lg * 4 + r;
      float mx = -1e30f;
#pragma unroll
      for (int nf = 0; nf < 4; ++nf) {
        int n = nf * 16 + li;
        int ridx = ((m >> 3) - (n >> 3) + 7) * 15 + (m & 7) - (n & 7) + 7;
        float val = s[mf][nf][r] * SC + btab[ridx * 12 + h] + mrow[m * 64 + n];
        s[mf][nf][r] = val;
        mx = fmaxf(mx, val);
      }
#pragma unroll
      for (int o2 = 1; o2 < 16; o2 <<= 1) mx = fmaxf(mx, __shfl_xor(mx, o2));
      float sum = 0.f;
#pragma unroll
      for (int nf = 0; nf < 4; ++nf) {
        float e = __expf(s[mf][nf][r] - mx);
        s[mf][nf][r] = e;
        sum += e;
      }
#pragma unroll
      for (int o2 = 1; o2 < 16; o2 <<= 1) sum += __shfl_xor(sum, o2);
      float inv = __builtin_amdgcn_rcpf(sum);
#pragma unroll
      for (int nf = 0; nf < 4; ++nf) s[mf][nf][r] *= inv;
    }
  }

#pragma unroll
  for (int mf = 0; mf < 4; ++mf)
#pragma unroll
    for (int nf = 0; nf < 4; ++nf)
#pragma unroll
      for (int r = 0; r < 4; ++r) {
        int m = mf * 16 + lg * 4 + r, n = nf * 16 + li;
        p_lds[wid][m * 72 + n] = f2bf(s[mf][nf][r]);
      }

  f32x4 o[4][2] = {};
#pragma unroll
  for (int kf = 0; kf < 2; ++kf) {
    bf16x8 bv[2];
#pragma unroll
    for (int df = 0; df < 2; ++df) {
      bf16x8 t;
#pragma unroll
      for (int e = 0; e < 8; ++e)
        t[e] = (short)v_lds[wid][(kf * 32 + lg * 8 + e) * 40 + df * 16 + li];
      bv[df] = t;
    }
#pragma unroll
    for (int mf = 0; mf < 4; ++mf) {
      bf16x8 pa = *(const bf16x8*)&p_lds[wid][(mf * 16 + li) * 72 + kf * 32 + lg * 8];
#pragma unroll
      for (int df = 0; df < 2; ++df)
        o[mf][df] = __builtin_amdgcn_mfma_f32_16x16x32_bf16(pa, bv[df], o[mf][df], 0, 0, 0);
    }
  }

#pragma unroll
  for (int mf = 0; mf < 4; ++mf)
#pragma unroll
    for (int df = 0; df < 2; ++df)
#pragma unroll
      for (int r = 0; r < 4; ++r) {
        size_t row = base + mf * 16 + lg * 4 + r;
        out[row * 384 + h * 32 + df * 16 + li] = f2bf(o[mf][df][r]);
      }
}

extern "C" void kernel_launch(void* const* d_in, const int* in_sizes, int n_in,
                              void* d_out, int out_size, void* d_ws, size_t ws_size,
                              hipStream_t stream) {
  const float* x      = (const float*)d_in[0];
  const float* qkv_w  = (const float*)d_in[1];
  const float* qkv_b  = (const float*)d_in[2];
  const float* proj_w = (const float*)d_in[3];
  const float* proj_b = (const float*)d_in[4];
  const float* rel    = (const float*)d_in[5];
  const float* g1     = (const float*)d_in[6];
  const float* b1     = (const float*)d_in[7];
  const float* g2     = (const float*)d_in[8];
  const float* b2     = (const float*)d_in[9];
  const float* fc1_w  = (const float*)d_in[10];
  const float* fc1_b  = (const float*)d_in[11];
  const float* fc2_w  = (const float*)d_in[12];
  const float* fc2_b  = (const float*)d_in[13];
  const float* mask   = (const float*)d_in[14];
  float* out = (float*)d_out;
  char* ws = (char*)d_ws;

  const int M = 131072;  // B * H * W tokens
  unsigned short* hw     = (unsigned short*)ws;
  unsigned short* qkv    = (unsigned short*)(ws + 100663296);
  unsigned short* hmid   = (unsigned short*)ws;
  unsigned short* attn_o = (unsigned short*)(ws + 402653184);
  unsigned short* ln2o   = attn_o;
  unsigned short* x1b    = (unsigned short*)(ws + 503316480);
  unsigned short* wq     = (unsigned short*)(ws + 603979776);
  unsigned short* wp     = wq + 442368;
  unsigned short* w1     = wp + 147456;
  unsigned short* w2     = w1 + 589824;
  unsigned short* xb     = (unsigned short*)(ws + 607518720);

  // fused weight casts (wq|wp|w1|w2 contiguous)
  cvt_all<<<(442368 + 147456 + 589824 + 589824 + 255) / 256, 256, 0, stream>>>(
      qkv_w, 442368, proj_w, 147456, fc1_w, 589824, fc2_w, 589824, wq);

  // LN1 + shift + window partition (also emits xb = bf16(x))
  ln_kernel<1><<<M / 4, 256, 0, stream>>>(x, g1, b1, hw, xb);

  // QKV projection: grid (M/256)*(1152/128) = 512*9
  gemmT<0, 384, 9><<<512 * 9, 512, 0, stream>>>(hw, wq, qkv_b, M, 1152, qkv, nullptr, nullptr);

  // windowed attention (one head-triple per block.y)
  attn_kernel<<<dim3(2048, 3), 256, 0, stream>>>(qkv, rel, mask, attn_o);

  // proj + window reverse + unshift + residual(xb bf16) -> x1 (bf16): 512*3
  gemmT<2, 384, 3><<<512 * 3, 512, 0, stream>>>(attn_o, wp, proj_b, M, 384, x1b, xb, nullptr);

  // LN2 (bf16 in)
  ln_bf16<<<M / 4, 256, 0, stream>>>(x1b, g2, b2, ln2o);

  // FC1 + GELU: 512*12
  gemmT<1, 384, 12><<<512 * 12, 512, 0, stream>>>(ln2o, w1, fc1_b, M, 1536, hmid, nullptr, nullptr);

  // FC2 + residual(x1 bf16) -> out (f32): 512*3
  gemmT<3, 1536, 3><<<512 * 3, 512, 0, stream>>>(hmid, w2, fc2_b, M, 384, nullptr, x1b, out);
}